// Round 1
// baseline (473.988 us; speedup 1.0000x reference)
//
#include <hip/hip_runtime.h>

typedef unsigned short ushort_t;
typedef __attribute__((ext_vector_type(8))) short short8;
typedef __attribute__((ext_vector_type(4))) float f32x4;
typedef __attribute__((ext_vector_type(4))) float float4v;
typedef __attribute__((ext_vector_type(4))) unsigned short ushortx4;
typedef __attribute__((ext_vector_type(2))) unsigned int uintx2;

#define AS1 __attribute__((address_space(1)))
#define AS3 __attribute__((address_space(3)))

#define B_ 4
#define N_ 2048
#define C_ 1024
#define H_ 16
#define HD_ 64
#define M_TOT 8192
#define N3_ 3072

__device__ __forceinline__ unsigned short f2bf(float f) {
    unsigned int u = __float_as_uint(f);
    u += 0x7fffu + ((u >> 16) & 1u);
    return (unsigned short)(u >> 16);
}

__global__ __launch_bounds__(256) void cast_f32_bf16(const float* __restrict__ in,
                                                     ushort_t* __restrict__ out, int n4) {
    int i = blockIdx.x * blockDim.x + threadIdx.x;
    int stride = gridDim.x * blockDim.x;
    for (; i < n4; i += stride) {
        float4v v = ((const float4v*)in)[i];
        ushortx4 o;
        o[0] = f2bf(v[0]); o[1] = f2bf(v[1]); o[2] = f2bf(v[2]); o[3] = f2bf(v[3]);
        ((ushortx4*)out)[i] = o;
    }
}

// C = A @ B^T, A [M][K] bf16 row-major, B [N][K] bf16 row-major. 128x128 tile, BK=32.
// EPI 0: scatter qkv -> q[bh][n][hd] (*0.125), k[bh][n][hd], vT[bh][hd][n]
// EPI 1: out f32 [M][1024] += bias
template <int EPI>
__global__ __launch_bounds__(256) void gemm_bt(const ushort_t* __restrict__ A,
                                               const ushort_t* __restrict__ Bw,
                                               ushort_t* __restrict__ o0,
                                               ushort_t* __restrict__ o1,
                                               ushort_t* __restrict__ o2,
                                               float* __restrict__ outf,
                                               const float* __restrict__ bias, int K) {
    __shared__ ushort_t As[2][128 * 32];
    __shared__ ushort_t Bs[2][128 * 32];
    const int tid = threadIdx.x;
    const int lane = tid & 63;
    const int wid = tid >> 6;
    const int l15 = lane & 15, lg = lane >> 4;
    const int wr = wid >> 1, wc = wid & 1;
    const int m0 = blockIdx.y * 128, n0 = blockIdx.x * 128;

    f32x4 acc[4][4] = {};

    auto stage = [&](int buf, int k0) {
        int row = tid >> 2;
        int ko = (tid & 3) * 8;
        const ushort_t* a0 = A + (size_t)(m0 + row) * K + k0 + ko;
        const ushort_t* b0 = Bw + (size_t)(n0 + row) * K + k0 + ko;
        char* la = (char*)(&As[buf][0]) + (tid & 192) * 16;  // wave-uniform base
        char* lb = (char*)(&Bs[buf][0]) + (tid & 192) * 16;
        __builtin_amdgcn_global_load_lds((const AS1 void*)a0, (AS3 void*)la, 16, 0, 0);
        __builtin_amdgcn_global_load_lds((const AS1 void*)(a0 + (size_t)64 * K),
                                         (AS3 void*)(la + 4096), 16, 0, 0);
        __builtin_amdgcn_global_load_lds((const AS1 void*)b0, (AS3 void*)lb, 16, 0, 0);
        __builtin_amdgcn_global_load_lds((const AS1 void*)(b0 + (size_t)64 * K),
                                         (AS3 void*)(lb + 4096), 16, 0, 0);
    };

    stage(0, 0);
    __syncthreads();
    const int NKI = K >> 5;
    for (int kt = 0; kt < NKI; ++kt) {
        const int cur = kt & 1;
        if (kt + 1 < NKI) stage(cur ^ 1, (kt + 1) << 5);
        short8 af[4], bf[4];
#pragma unroll
        for (int mi = 0; mi < 4; ++mi)
            af[mi] = *(const short8*)(&As[cur][(wr * 64 + mi * 16 + l15) * 32 + lg * 8]);
#pragma unroll
        for (int ni = 0; ni < 4; ++ni)
            bf[ni] = *(const short8*)(&Bs[cur][(wc * 64 + ni * 16 + l15) * 32 + lg * 8]);
#pragma unroll
        for (int mi = 0; mi < 4; ++mi)
#pragma unroll
            for (int ni = 0; ni < 4; ++ni)
                acc[mi][ni] = __builtin_amdgcn_mfma_f32_16x16x32_bf16(af[mi], bf[ni],
                                                                      acc[mi][ni], 0, 0, 0);
        __syncthreads();
    }

    if (EPI == 0) {
        const int sel = blockIdx.x >> 3;  // 0=q 1=k 2=v, uniform per block
        const int cb = (blockIdx.x & 7) * 128 + wc * 64;
#pragma unroll
        for (int mi = 0; mi < 4; ++mi) {
            const int r0 = m0 + wr * 64 + mi * 16 + lg * 4;
            const int b = r0 >> 11, n = r0 & 2047;
#pragma unroll
            for (int ni = 0; ni < 4; ++ni) {
                const int c = cb + ni * 16 + l15;
                const int h = c >> 6, hd = c & 63;
                const size_t bh = (size_t)(b * H_ + h);
                f32x4 a = acc[mi][ni];
                if (sel == 0) {
#pragma unroll
                    for (int j = 0; j < 4; ++j)
                        o0[(bh * N_ + (n + j)) * HD_ + hd] = f2bf(a[j] * 0.125f);
                } else if (sel == 1) {
#pragma unroll
                    for (int j = 0; j < 4; ++j)
                        o1[(bh * N_ + (n + j)) * HD_ + hd] = f2bf(a[j]);
                } else {
                    ushortx4 pk;
#pragma unroll
                    for (int j = 0; j < 4; ++j) pk[j] = f2bf(a[j]);
                    *(ushortx4*)(&o2[(bh * HD_ + hd) * N_ + n]) = pk;
                }
            }
        }
    } else {
#pragma unroll
        for (int ni = 0; ni < 4; ++ni) {
            const int c = n0 + wc * 64 + ni * 16 + l15;
            const float bv = bias[c];
#pragma unroll
            for (int mi = 0; mi < 4; ++mi) {
                const int r0 = m0 + wr * 64 + mi * 16 + lg * 4;
                f32x4 a = acc[mi][ni];
#pragma unroll
                for (int j = 0; j < 4; ++j)
                    outf[(size_t)(r0 + j) * C_ + c] = a[j] + bv;
            }
        }
    }
}

// Flash attention. grid (16 qtiles, 64 bh), 4 waves x 32 q-rows.
// Q/K [bh][n][64] bf16 (q pre-scaled), vT [bh][64][n] bf16. Out vhat [b*N][C] bf16.
__global__ __launch_bounds__(256) void attn_fwd(const ushort_t* __restrict__ Q,
                                                const ushort_t* __restrict__ Kt,
                                                const ushort_t* __restrict__ Vt,
                                                ushort_t* __restrict__ Ov) {
    __shared__ ushort_t P_lds[4][32 * 64];
    const int tid = threadIdx.x;
    const int lane = tid & 63;
    const int wid = tid >> 6;
    const int l15 = lane & 15, lg = lane >> 4;
    const int bh = blockIdx.y;
    const int qbase = blockIdx.x * 128 + wid * 32;
    const ushort_t* qp = Q + (size_t)bh * N_ * HD_;
    const ushort_t* kp = Kt + (size_t)bh * N_ * HD_;
    const ushort_t* vp = Vt + (size_t)bh * HD_ * N_;
    char* pl = (char*)(&P_lds[wid][0]);

    short8 qf[2][2];
#pragma unroll
    for (int qi = 0; qi < 2; ++qi)
#pragma unroll
        for (int kk = 0; kk < 2; ++kk)
            qf[qi][kk] = *(const short8*)(qp + (size_t)(qbase + qi * 16 + l15) * HD_ +
                                          kk * 32 + lg * 8);

    f32x4 oacc[4][2] = {};
    float mrun[2] = {-INFINITY, -INFINITY};
    float srun[2] = {0.f, 0.f};

    for (int kv0 = 0; kv0 < N_; kv0 += 64) {
        // S^T[kv][q] = K . Q^T  (swapped operands: row=kv, col=q)
        f32x4 sacc[4][2] = {};
#pragma unroll
        for (int kvi = 0; kvi < 4; ++kvi)
#pragma unroll
            for (int kk = 0; kk < 2; ++kk) {
                short8 kf = *(const short8*)(kp + (size_t)(kv0 + kvi * 16 + l15) * HD_ +
                                             kk * 32 + lg * 8);
#pragma unroll
                for (int qi = 0; qi < 2; ++qi)
                    sacc[kvi][qi] = __builtin_amdgcn_mfma_f32_16x16x32_bf16(
                        kf, qf[qi][kk], sacc[kvi][qi], 0, 0, 0);
            }

        // online softmax per q-column (col = l15 within tile qi)
#pragma unroll
        for (int qi = 0; qi < 2; ++qi) {
            float pm = -INFINITY;
#pragma unroll
            for (int kvi = 0; kvi < 4; ++kvi)
#pragma unroll
                for (int j = 0; j < 4; ++j) pm = fmaxf(pm, sacc[kvi][qi][j]);
            pm = fmaxf(pm, __shfl_xor(pm, 16, 64));
            pm = fmaxf(pm, __shfl_xor(pm, 32, 64));
            const float mn = fmaxf(mrun[qi], pm);
            const float corr = __expf(mrun[qi] - mn);
            mrun[qi] = mn;
            float rs = 0.f;
            const int qrow = qi * 16 + l15;
            const int swz = (qrow & 7) << 4;
#pragma unroll
            for (int kvi = 0; kvi < 4; ++kvi) {
                float p0 = __expf(sacc[kvi][qi][0] - mn);
                float p1 = __expf(sacc[kvi][qi][1] - mn);
                float p2 = __expf(sacc[kvi][qi][2] - mn);
                float p3 = __expf(sacc[kvi][qi][3] - mn);
                rs += (p0 + p1) + (p2 + p3);
                uintx2 w;
                w[0] = (unsigned)f2bf(p0) | ((unsigned)f2bf(p1) << 16);
                w[1] = (unsigned)f2bf(p2) | ((unsigned)f2bf(p3) << 16);
                int off = qrow * 128 + (kvi * 16 + lg * 4) * 2;
                *(uintx2*)(pl + (off ^ swz)) = w;
            }
            rs += __shfl_xor(rs, 16, 64);
            rs += __shfl_xor(rs, 32, 64);
            srun[qi] = srun[qi] * corr + rs;
#pragma unroll
            for (int di = 0; di < 4; ++di) oacc[di][qi] *= corr;
        }

        // PV: vhat^T[d][q] += V^T . P^T  (A = vT rows d, B = P from LDS)
#pragma unroll
        for (int kk2 = 0; kk2 < 2; ++kk2) {
            short8 pf[2];
#pragma unroll
            for (int qi = 0; qi < 2; ++qi) {
                const int qrow = qi * 16 + l15;
                int off = qrow * 128 + kk2 * 64 + lg * 16;
                pf[qi] = *(const short8*)(pl + (off ^ ((qrow & 7) << 4)));
            }
#pragma unroll
            for (int di = 0; di < 4; ++di) {
                short8 vf = *(const short8*)(vp + (size_t)(di * 16 + l15) * N_ + kv0 +
                                             kk2 * 32 + lg * 8);
#pragma unroll
                for (int qi = 0; qi < 2; ++qi)
                    oacc[di][qi] = __builtin_amdgcn_mfma_f32_16x16x32_bf16(
                        vf, pf[qi], oacc[di][qi], 0, 0, 0);
            }
        }
    }

    const int b = bh >> 4, h = bh & 15;
#pragma unroll
    for (int qi = 0; qi < 2; ++qi) {
        const float inv = 1.f / srun[qi];
        const int qg = qbase + qi * 16 + l15;
#pragma unroll
        for (int di = 0; di < 4; ++di) {
            ushortx4 pk;
#pragma unroll
            for (int j = 0; j < 4; ++j) pk[j] = f2bf(oacc[di][qi][j] * inv);
            *(ushortx4*)(&Ov[((size_t)(b * N_ + qg)) * C_ + h * HD_ + di * 16 + lg * 4]) = pk;
        }
    }
}

extern "C" void kernel_launch(void* const* d_in, const int* in_sizes, int n_in,
                              void* d_out, int out_size, void* d_ws, size_t ws_size,
                              hipStream_t stream) {
    const float* x = (const float*)d_in[0];
    const float* wqkv = (const float*)d_in[1];
    const float* wout = (const float*)d_in[2];
    const float* bout = (const float*)d_in[3];
    float* out = (float*)d_out;

    ushort_t* ws = (ushort_t*)d_ws;
    const size_t XN = (size_t)M_TOT * C_;       // 8388608
    const size_t WQN = (size_t)N3_ * C_;        // 3145728
    const size_t WON = (size_t)C_ * C_;         // 1048576
    ushort_t* xbf = ws;                         // also reused as vhat after gemm1
    ushort_t* wqkvb = xbf + XN;
    ushort_t* woutb = wqkvb + WQN;
    ushort_t* qarr = woutb + WON;
    ushort_t* karr = qarr + XN;
    ushort_t* vtarr = karr + XN;
    ushort_t* vhat = xbf;  // alias: x_bf dead after gemm1

    cast_f32_bf16<<<2048, 256, 0, stream>>>(x, xbf, (int)(XN / 4));
    cast_f32_bf16<<<1024, 256, 0, stream>>>(wqkv, wqkvb, (int)(WQN / 4));
    cast_f32_bf16<<<512, 256, 0, stream>>>(wout, woutb, (int)(WON / 4));

    gemm_bt<0><<<dim3(24, 64), 256, 0, stream>>>(xbf, wqkvb, qarr, karr, vtarr,
                                                 nullptr, nullptr, C_);
    attn_fwd<<<dim3(16, 64), 256, 0, stream>>>(qarr, karr, vtarr, vhat);
    gemm_bt<1><<<dim3(8, 64), 256, 0, stream>>>(vhat, woutb, nullptr, nullptr, nullptr,
                                                out, bout, C_);
}

// Round 2
// 342.706 us; speedup vs baseline: 1.3831x; 1.3831x over previous
//
#include <hip/hip_runtime.h>

typedef unsigned short ushort_t;
typedef __attribute__((ext_vector_type(8))) short short8;
typedef __attribute__((ext_vector_type(4))) float f32x4;
typedef __attribute__((ext_vector_type(4))) float float4v;
typedef __attribute__((ext_vector_type(4))) unsigned short ushortx4;
typedef __attribute__((ext_vector_type(2))) unsigned int uintx2;

#define AS1 __attribute__((address_space(1)))
#define AS3 __attribute__((address_space(3)))

#define B_ 4
#define N_ 2048
#define C_ 1024
#define H_ 16
#define HD_ 64
#define M_TOT 8192
#define N3_ 3072

// q scale: 1/sqrt(64) * log2(e) so softmax runs in exp2 domain
#define QSCALE 0.18033688011112042f

__device__ __forceinline__ unsigned short f2bf(float f) {
    unsigned int u = __float_as_uint(f);
    u += 0x7fffu + ((u >> 16) & 1u);
    return (unsigned short)(u >> 16);
}

__global__ __launch_bounds__(256) void cast_f32_bf16(const float* __restrict__ in,
                                                     ushort_t* __restrict__ out, int n4) {
    int i = blockIdx.x * blockDim.x + threadIdx.x;
    int stride = gridDim.x * blockDim.x;
    for (; i < n4; i += stride) {
        float4v v = ((const float4v*)in)[i];
        ushortx4 o;
        o[0] = f2bf(v[0]); o[1] = f2bf(v[1]); o[2] = f2bf(v[2]); o[3] = f2bf(v[3]);
        ((ushortx4*)out)[i] = o;
    }
}

// C = A @ B^T, A [M][K] bf16 row-major, B [N][K] bf16 row-major. 128x128 tile, BK=32.
// EPI 0: scatter qkv -> q[bh][n][hd] (*QSCALE), k[bh][n][hd], vT[bh][hd][n]
// EPI 1: out f32 [M][1024] += bias
template <int EPI>
__global__ __launch_bounds__(256) void gemm_bt(const ushort_t* __restrict__ A,
                                               const ushort_t* __restrict__ Bw,
                                               ushort_t* __restrict__ o0,
                                               ushort_t* __restrict__ o1,
                                               ushort_t* __restrict__ o2,
                                               float* __restrict__ outf,
                                               const float* __restrict__ bias, int K) {
    __shared__ ushort_t As[2][128 * 32];
    __shared__ ushort_t Bs[2][128 * 32];
    const int tid = threadIdx.x;
    const int lane = tid & 63;
    const int wid = tid >> 6;
    const int l15 = lane & 15, lg = lane >> 4;
    const int wr = wid >> 1, wc = wid & 1;
    const int m0 = blockIdx.y * 128, n0 = blockIdx.x * 128;

    f32x4 acc[4][4] = {};

    auto stage = [&](int buf, int k0) {
        int row = tid >> 2;
        int ko = (tid & 3) * 8;
        const ushort_t* a0 = A + (size_t)(m0 + row) * K + k0 + ko;
        const ushort_t* b0 = Bw + (size_t)(n0 + row) * K + k0 + ko;
        char* la = (char*)(&As[buf][0]) + (tid & 192) * 16;  // wave-uniform base
        char* lb = (char*)(&Bs[buf][0]) + (tid & 192) * 16;
        __builtin_amdgcn_global_load_lds((const AS1 void*)a0, (AS3 void*)la, 16, 0, 0);
        __builtin_amdgcn_global_load_lds((const AS1 void*)(a0 + (size_t)64 * K),
                                         (AS3 void*)(la + 4096), 16, 0, 0);
        __builtin_amdgcn_global_load_lds((const AS1 void*)b0, (AS3 void*)lb, 16, 0, 0);
        __builtin_amdgcn_global_load_lds((const AS1 void*)(b0 + (size_t)64 * K),
                                         (AS3 void*)(lb + 4096), 16, 0, 0);
    };

    stage(0, 0);
    __syncthreads();
    const int NKI = K >> 5;
    for (int kt = 0; kt < NKI; ++kt) {
        const int cur = kt & 1;
        if (kt + 1 < NKI) stage(cur ^ 1, (kt + 1) << 5);
        short8 af[4], bf[4];
#pragma unroll
        for (int mi = 0; mi < 4; ++mi)
            af[mi] = *(const short8*)(&As[cur][(wr * 64 + mi * 16 + l15) * 32 + lg * 8]);
#pragma unroll
        for (int ni = 0; ni < 4; ++ni)
            bf[ni] = *(const short8*)(&Bs[cur][(wc * 64 + ni * 16 + l15) * 32 + lg * 8]);
#pragma unroll
        for (int mi = 0; mi < 4; ++mi)
#pragma unroll
            for (int ni = 0; ni < 4; ++ni)
                acc[mi][ni] = __builtin_amdgcn_mfma_f32_16x16x32_bf16(af[mi], bf[ni],
                                                                      acc[mi][ni], 0, 0, 0);
        __syncthreads();
    }

    if (EPI == 0) {
        const int sel = blockIdx.x >> 3;  // 0=q 1=k 2=v, uniform per block
        const int cb = (blockIdx.x & 7) * 128 + wc * 64;
#pragma unroll
        for (int mi = 0; mi < 4; ++mi) {
            const int r0 = m0 + wr * 64 + mi * 16 + lg * 4;
            const int b = r0 >> 11, n = r0 & 2047;
#pragma unroll
            for (int ni = 0; ni < 4; ++ni) {
                const int c = cb + ni * 16 + l15;
                const int h = c >> 6, hd = c & 63;
                const size_t bh = (size_t)(b * H_ + h);
                f32x4 a = acc[mi][ni];
                if (sel == 0) {
#pragma unroll
                    for (int j = 0; j < 4; ++j)
                        o0[(bh * N_ + (n + j)) * HD_ + hd] = f2bf(a[j] * QSCALE);
                } else if (sel == 1) {
#pragma unroll
                    for (int j = 0; j < 4; ++j)
                        o1[(bh * N_ + (n + j)) * HD_ + hd] = f2bf(a[j]);
                } else {
                    ushortx4 pk;
#pragma unroll
                    for (int j = 0; j < 4; ++j) pk[j] = f2bf(a[j]);
                    *(ushortx4*)(&o2[(bh * HD_ + hd) * N_ + n]) = pk;
                }
            }
        }
    } else {
#pragma unroll
        for (int ni = 0; ni < 4; ++ni) {
            const int c = n0 + wc * 64 + ni * 16 + l15;
            const float bv = bias[c];
#pragma unroll
            for (int mi = 0; mi < 4; ++mi) {
                const int r0 = m0 + wr * 64 + mi * 16 + lg * 4;
                f32x4 a = acc[mi][ni];
#pragma unroll
                for (int j = 0; j < 4; ++j)
                    outf[(size_t)(r0 + j) * C_ + c] = a[j] + bv;
            }
        }
    }
}

// Flash attention v2: 1D grid 1024 blocks, XCD-swizzled so each bh's 16 q-tiles
// stay on one XCD (K/V L2-resident). 4 waves x 32 q-rows, KVBLK=32,
// register-pipelined K (2-stage ping-pong) and V (issued before softmax).
// Q/K [bh][n][64] bf16 (q pre-scaled by QSCALE), vT [bh][64][n] bf16.
__global__ __launch_bounds__(256) void attn_fwd(const ushort_t* __restrict__ Q,
                                                const ushort_t* __restrict__ Kt,
                                                const ushort_t* __restrict__ Vt,
                                                ushort_t* __restrict__ Ov) {
    __shared__ ushort_t P_lds[4][32 * 32];  // per-wave 2KB P buffer (no barriers)
    const int tid = threadIdx.x;
    const int lane = tid & 63;
    const int wid = tid >> 6;
    const int l15 = lane & 15, lg = lane >> 4;

    // XCD swizzle: wg -> (xcd, slot); bh = xcd*8 + slot/16, qt = slot%16
    const int wg = blockIdx.x;
    const int xcd = wg & 7, slot = wg >> 3;
    const int bh = xcd * 8 + (slot >> 4);
    const int qt = slot & 15;

    const int qbase = qt * 128 + wid * 32;
    const ushort_t* qp = Q + (size_t)bh * N_ * HD_;
    const ushort_t* kp = Kt + (size_t)bh * N_ * HD_;
    const ushort_t* vp = Vt + (size_t)bh * HD_ * N_;
    char* pl = (char*)(&P_lds[wid][0]);

    short8 qf[2][2];
#pragma unroll
    for (int qi = 0; qi < 2; ++qi)
#pragma unroll
        for (int kk = 0; kk < 2; ++kk)
            qf[qi][kk] = *(const short8*)(qp + (size_t)(qbase + qi * 16 + l15) * HD_ +
                                          kk * 32 + lg * 8);

    f32x4 oacc[4][2] = {};
    float mrun[2] = {-INFINITY, -INFINITY};
    float srun[2] = {0.f, 0.f};

    const int NT = N_ / 32;  // 64 tiles

    // K fragment prologue: tile 0 into kfA
    short8 kfA[4], kfB[4];
#pragma unroll
    for (int kvi = 0; kvi < 2; ++kvi)
#pragma unroll
        for (int kk = 0; kk < 2; ++kk)
            kfA[kvi * 2 + kk] = *(const short8*)(kp + (size_t)(kvi * 16 + l15) * HD_ +
                                                 kk * 32 + lg * 8);

    auto iter = [&](short8(&kfu)[4], short8(&kfp)[4], int t) {
        const int kv0 = t << 5;
        // issue V loads for this tile (consumed after softmax, ~250cy cover)
        short8 vf[4];
#pragma unroll
        for (int di = 0; di < 4; ++di)
            vf[di] = *(const short8*)(vp + (size_t)(di * 16 + l15) * N_ + kv0 + lg * 8);

        // QK^T (swapped): S^T[kv][q], 8 MFMAs
        f32x4 sacc[2][2] = {};
#pragma unroll
        for (int kvi = 0; kvi < 2; ++kvi)
#pragma unroll
            for (int kk = 0; kk < 2; ++kk)
#pragma unroll
                for (int qi = 0; qi < 2; ++qi)
                    sacc[kvi][qi] = __builtin_amdgcn_mfma_f32_16x16x32_bf16(
                        kfu[kvi * 2 + kk], qf[qi][kk], sacc[kvi][qi], 0, 0, 0);

        // prefetch next K tile (consumed next iteration, ~full-iter cover)
        const int kvn = ((t + 1) & (NT - 1)) << 5;
#pragma unroll
        for (int kvi = 0; kvi < 2; ++kvi)
#pragma unroll
            for (int kk = 0; kk < 2; ++kk)
                kfp[kvi * 2 + kk] = *(const short8*)(kp + (size_t)(kvn + kvi * 16 + l15) * HD_ +
                                                     kk * 32 + lg * 8);

        // online softmax (exp2 domain), defer-max THR=8
#pragma unroll
        for (int qi = 0; qi < 2; ++qi) {
            float pm = sacc[0][qi][0];
            pm = fmaxf(pm, sacc[0][qi][1]);
            pm = fmaxf(pm, sacc[0][qi][2]);
            pm = fmaxf(pm, sacc[0][qi][3]);
            pm = fmaxf(pm, sacc[1][qi][0]);
            pm = fmaxf(pm, sacc[1][qi][1]);
            pm = fmaxf(pm, sacc[1][qi][2]);
            pm = fmaxf(pm, sacc[1][qi][3]);
            pm = fmaxf(pm, __shfl_xor(pm, 16, 64));
            pm = fmaxf(pm, __shfl_xor(pm, 32, 64));
            if (!__all(pm - mrun[qi] <= 8.f)) {
                const float mn = fmaxf(mrun[qi], pm);
                const float corr = exp2f(mrun[qi] - mn);
                mrun[qi] = mn;
                srun[qi] *= corr;
#pragma unroll
                for (int di = 0; di < 4; ++di) oacc[di][qi] *= corr;
            }
            const int qrow = qi * 16 + l15;
            const int swz = (qrow & 3) << 4;
            float rs = 0.f;
#pragma unroll
            for (int kvi = 0; kvi < 2; ++kvi) {
                float p0 = exp2f(sacc[kvi][qi][0] - mrun[qi]);
                float p1 = exp2f(sacc[kvi][qi][1] - mrun[qi]);
                float p2 = exp2f(sacc[kvi][qi][2] - mrun[qi]);
                float p3 = exp2f(sacc[kvi][qi][3] - mrun[qi]);
                rs += (p0 + p1) + (p2 + p3);
                uintx2 w;
                w[0] = (unsigned)f2bf(p0) | ((unsigned)f2bf(p1) << 16);
                w[1] = (unsigned)f2bf(p2) | ((unsigned)f2bf(p3) << 16);
                *(uintx2*)(pl + qrow * 64 + ((kvi * 32 + lg * 8) ^ swz)) = w;
            }
            rs += __shfl_xor(rs, 16, 64);
            rs += __shfl_xor(rs, 32, 64);
            srun[qi] += rs;
        }

        // P read + PV: vhat^T[d][q] += V^T . P^T, 8 MFMAs
        short8 pf[2];
#pragma unroll
        for (int qi = 0; qi < 2; ++qi) {
            const int qrow = qi * 16 + l15;
            pf[qi] = *(const short8*)(pl + qrow * 64 + ((lg * 16) ^ ((qrow & 3) << 4)));
        }
#pragma unroll
        for (int di = 0; di < 4; ++di)
#pragma unroll
            for (int qi = 0; qi < 2; ++qi)
                oacc[di][qi] = __builtin_amdgcn_mfma_f32_16x16x32_bf16(
                    vf[di], pf[qi], oacc[di][qi], 0, 0, 0);
    };

    for (int t2 = 0; t2 < NT; t2 += 2) {
        iter(kfA, kfB, t2);
        iter(kfB, kfA, t2 + 1);
    }

    const int b = bh >> 4, h = bh & 15;
#pragma unroll
    for (int qi = 0; qi < 2; ++qi) {
        const float inv = 1.f / srun[qi];
        const int qg = qbase + qi * 16 + l15;
#pragma unroll
        for (int di = 0; di < 4; ++di) {
            ushortx4 pk;
#pragma unroll
            for (int j = 0; j < 4; ++j) pk[j] = f2bf(oacc[di][qi][j] * inv);
            *(ushortx4*)(&Ov[((size_t)(b * N_ + qg)) * C_ + h * HD_ + di * 16 + lg * 4]) = pk;
        }
    }
}

extern "C" void kernel_launch(void* const* d_in, const int* in_sizes, int n_in,
                              void* d_out, int out_size, void* d_ws, size_t ws_size,
                              hipStream_t stream) {
    const float* x = (const float*)d_in[0];
    const float* wqkv = (const float*)d_in[1];
    const float* wout = (const float*)d_in[2];
    const float* bout = (const float*)d_in[3];
    float* out = (float*)d_out;

    ushort_t* ws = (ushort_t*)d_ws;
    const size_t XN = (size_t)M_TOT * C_;       // 8388608
    const size_t WQN = (size_t)N3_ * C_;        // 3145728
    const size_t WON = (size_t)C_ * C_;         // 1048576
    ushort_t* xbf = ws;                         // also reused as vhat after gemm1
    ushort_t* wqkvb = xbf + XN;
    ushort_t* woutb = wqkvb + WQN;
    ushort_t* qarr = woutb + WON;
    ushort_t* karr = qarr + XN;
    ushort_t* vtarr = karr + XN;
    ushort_t* vhat = xbf;  // alias: x_bf dead after gemm1

    cast_f32_bf16<<<2048, 256, 0, stream>>>(x, xbf, (int)(XN / 4));
    cast_f32_bf16<<<1024, 256, 0, stream>>>(wqkv, wqkvb, (int)(WQN / 4));
    cast_f32_bf16<<<512, 256, 0, stream>>>(wout, woutb, (int)(WON / 4));

    gemm_bt<0><<<dim3(24, 64), 256, 0, stream>>>(xbf, wqkvb, qarr, karr, vtarr,
                                                 nullptr, nullptr, C_);
    attn_fwd<<<1024, 256, 0, stream>>>(qarr, karr, vtarr, vhat);
    gemm_bt<1><<<dim3(8, 64), 256, 0, stream>>>(vhat, woutb, nullptr, nullptr, nullptr,
                                                out, bout, C_);
}